// Round 3
// baseline (1223.418 us; speedup 1.0000x reference)
//
#include <hip/hip_runtime.h>

// ---------------------------------------------------------------------------
// SpectrumGenerator: 5-layer MLP (leaky_relu 0.2) + linear interp.
// dims: 128 -> 512 -> 1024 -> 2048 -> 4096 -> 35582 ; batch 64 ; 4096 obs pts
//
// R5 changes vs R4:
//  - REVERT the gemm/epilogue fusion (R4 regression: S_in x-block-redundant
//    partial re-reads ~300 MB + reduction chain on the staging critical path).
//    Partials are reduced exactly once again (R2 semantics, bit-identical).
//  - fc chain (4 gemms + 4 epis) fused into ONE persistent kernel:
//    256 blocks x 512 thr (1 block/CU guaranteed: 35 KB LDS, 8 waves),
//    half-block = one 64x64 tile job (R2's verified gemm body), stages
//    separated by 7 device-scope generation barriers (timeout-guarded spin).
//    Dispatches: 11 (R2) -> 4.
//  - keep R4's analytic searchsorted interp + sorted-column layer4 (both
//    verified exact in R4: absmax identical to R2).
// ---------------------------------------------------------------------------

#define NOUT   35582
#define BATCH  64
#define NOBS   4096
#define ROT    25604   // count of low-wavelength block (sorted first)
#define HIOFF  9978    // orig offset of low-wavelength block

typedef __bf16 bf16_t;
typedef __attribute__((ext_vector_type(8))) __bf16 bf16x8;
typedef __attribute__((ext_vector_type(4))) __bf16 bf16x4;
typedef __attribute__((ext_vector_type(4))) float f32x4;

__device__ __forceinline__ int sorted_to_orig(int p) {
    return (p < ROT) ? (p + HIOFF) : (p - ROT);
}

// ---------------- device-scope grid barrier (generation-based) -------------
// sync[0]=arrive counter, sync[1]=generation. Re-initialized per iteration by
// init_sync (workspace is poisoned each run). Timeout so a co-residency
// failure degrades to wrong-answer, never a hang.
__device__ __forceinline__ void gbar(unsigned* cnt, unsigned* gen, unsigned nb)
{
    __syncthreads();
    if (threadIdx.x == 0) {
        __threadfence();
        unsigned g = __hip_atomic_load(gen, __ATOMIC_ACQUIRE, __HIP_MEMORY_SCOPE_AGENT);
        unsigned a = __hip_atomic_fetch_add(cnt, 1u, __ATOMIC_ACQ_REL, __HIP_MEMORY_SCOPE_AGENT);
        if (a + 1u == nb) {
            __hip_atomic_store(cnt, 0u, __ATOMIC_RELAXED, __HIP_MEMORY_SCOPE_AGENT);
            __hip_atomic_fetch_add(gen, 1u, __ATOMIC_RELEASE, __HIP_MEMORY_SCOPE_AGENT);
        } else {
            long long t0 = clock64();
            while (__hip_atomic_load(gen, __ATOMIC_ACQUIRE, __HIP_MEMORY_SCOPE_AGENT) == g) {
                __builtin_amdgcn_s_sleep(2);
                if (clock64() - t0 > 200000000LL) break;   // bounded spin
            }
        }
        __threadfence();
    }
    __syncthreads();
}

__global__ void init_sync(unsigned* sync) { sync[0] = 0u; sync[1] = 0u; }

// ---------------- half-block 64x64 tile partial GEMM (R2 body) -------------
// t in [0,256). part[by] += ... no: partials written once per (bx,by) job.
__device__ __forceinline__ void gemm_half(
    int t, float (*As)[68], float (*Bs)[68],
    const float* __restrict__ A, const float* __restrict__ W,
    float* __restrict__ partOut, int K, int N, int KC, int lgx, int job)
{
    const int bx = job & ((1 << lgx) - 1);
    const int by = job >> lgx;
    const int n0 = bx * 64;
    const int kbase = by * KC;
    const int tx = t & 15;
    const int ty = t >> 4;

    float acc[4][4] = {};

    for (int k0 = kbase; k0 < kbase + KC; k0 += 32) {
        __syncthreads();
#pragma unroll
        for (int f = 0; f < 2; ++f) {
            int e  = (t + 256 * f) * 4;
            int m  = e >> 5;
            int kk = e & 31;
            float4 v = *(const float4*)(A + (size_t)m * K + k0 + kk);
            As[kk + 0][m] = v.x; As[kk + 1][m] = v.y;
            As[kk + 2][m] = v.z; As[kk + 3][m] = v.w;
        }
#pragma unroll
        for (int f = 0; f < 2; ++f) {
            int e  = (t + 256 * f) * 4;
            int n  = e >> 5;
            int kk = e & 31;
            float4 v = *(const float4*)(W + (size_t)(n0 + n) * K + k0 + kk);
            Bs[kk + 0][n] = v.x; Bs[kk + 1][n] = v.y;
            Bs[kk + 2][n] = v.z; Bs[kk + 3][n] = v.w;
        }
        __syncthreads();
#pragma unroll
        for (int kk = 0; kk < 32; ++kk) {
            float4 av = *(const float4*)&As[kk][ty * 4];
            float4 bv = *(const float4*)&Bs[kk][tx * 4];
            float a[4] = {av.x, av.y, av.z, av.w};
            float b[4] = {bv.x, bv.y, bv.z, bv.w};
#pragma unroll
            for (int i = 0; i < 4; ++i)
#pragma unroll
                for (int j = 0; j < 4; ++j) acc[i][j] += a[i] * b[j];
        }
    }

    float* p = partOut + (size_t)by * 64 * N;
#pragma unroll
    for (int i = 0; i < 4; ++i) {
        int m = ty * 4 + i;
#pragma unroll
        for (int j = 0; j < 4; ++j)
            p[(size_t)m * N + n0 + tx * 4 + j] = acc[i][j];
    }
}

// ---------------- epilogue stage: h = leaky(sum_s part[s] + b) -------------
// grid-stride over flattened 64xN in float4 units; all 256x512 threads.
__device__ __forceinline__ void epi_stage(
    const float* __restrict__ part, const float* __restrict__ bias,
    float* __restrict__ out, bf16_t* __restrict__ out_bf, int N, int S)
{
    int tot = 16 * N;                       // (64*N)/4 float4 elements
    int stride = gridDim.x * blockDim.x;
    for (int i = blockIdx.x * blockDim.x + threadIdx.x; i < tot; i += stride) {
        int idx = i * 4;
        int n = idx & (N - 1);              // N is a power of 2
        float4 v = make_float4(0.f, 0.f, 0.f, 0.f);
        for (int s = 0; s < S; ++s) {
            float4 p = *(const float4*)(part + (size_t)s * 64 * N + idx);
            v.x += p.x; v.y += p.y; v.z += p.z; v.w += p.w;
        }
        float4 b = *(const float4*)(bias + n);
        v.x += b.x; v.y += b.y; v.z += b.z; v.w += b.w;
        v.x = v.x > 0.f ? v.x : 0.2f * v.x;
        v.y = v.y > 0.f ? v.y : 0.2f * v.y;
        v.z = v.z > 0.f ? v.z : 0.2f * v.z;
        v.w = v.w > 0.f ? v.w : 0.2f * v.w;
        if (out) *(float4*)(out + idx) = v;
        if (out_bf) {
            bf16x4 o;
            o[0] = (bf16_t)v.x; o[1] = (bf16_t)v.y;
            o[2] = (bf16_t)v.z; o[3] = (bf16_t)v.w;
            *(bf16x4*)(out_bf + idx) = o;
        }
    }
}

// ---------------- fused fc chain: L0..L3 + epilogues, 7 grid barriers ------
// 256 blocks x 512 threads. Half-block (256 thr) = one tile job; job counts
// are even and assigned contiguously, so each block is fully active or fully
// idle in every gemm stage (syncthreads stays uniform).
__global__ __launch_bounds__(512, 2) void fc_fused(
    const float* __restrict__ z,
    const float* __restrict__ W0, const float* __restrict__ b0,
    const float* __restrict__ W1, const float* __restrict__ b1,
    const float* __restrict__ W2, const float* __restrict__ b2,
    const float* __restrict__ W3, const float* __restrict__ b3,
    float* __restrict__ pA, float* __restrict__ pB,
    float* __restrict__ h1, float* __restrict__ h2, float* __restrict__ h3,
    bf16_t* __restrict__ h4b, unsigned* __restrict__ sync)
{
    __shared__ float As[2][32][68];
    __shared__ float Bs[2][32][68];
    const int hh = threadIdx.x >> 8;        // half-block id
    const int t  = threadIdx.x & 255;
    const int job = blockIdx.x * 2 + hh;
    unsigned* cnt = sync;
    unsigned* gen = sync + 1;
    const unsigned NB = gridDim.x;

    // L0: K=128,  N=512,  KC=32,  jobs 8x4  = 32
    if (job < 32)  gemm_half(t, As[hh], Bs[hh], z,  W0, pA, 128,  512,  32,  3, job);
    gbar(cnt, gen, NB);
    epi_stage(pA, b0, h1, nullptr, 512, 4);
    gbar(cnt, gen, NB);
    // L1: K=512,  N=1024, KC=64,  jobs 16x8 = 128
    if (job < 128) gemm_half(t, As[hh], Bs[hh], h1, W1, pB, 512,  1024, 64,  4, job);
    gbar(cnt, gen, NB);
    epi_stage(pB, b1, h2, nullptr, 1024, 8);
    gbar(cnt, gen, NB);
    // L2: K=1024, N=2048, KC=128, jobs 32x8 = 256
    if (job < 256) gemm_half(t, As[hh], Bs[hh], h2, W2, pA, 1024, 2048, 128, 5, job);
    gbar(cnt, gen, NB);
    epi_stage(pA, b2, h3, nullptr, 2048, 8);
    gbar(cnt, gen, NB);
    // L3: K=2048, N=4096, KC=256, jobs 64x8 = 512
    if (job < 512) gemm_half(t, As[hh], Bs[hh], h3, W3, pB, 2048, 4096, 256, 6, job);
    gbar(cnt, gen, NB);
    epi_stage(pB, b3, nullptr, h4b, 4096, 8);
}

// ---------------- layer 4: spec_sorted = Abf(64x4096) @ W4^T + b4 ----------
// mfma_f32_16x16x32_bf16. Wave handles 16 consecutive SORTED cols p; the W4
// row is sorted_to_orig(p) (two contiguous runs -> streaming stays coalesced).
__global__ __launch_bounds__(256) void layer4_kernel(
    const bf16_t* __restrict__ Abf, const float* __restrict__ W,
    const float* __restrict__ bias, float* __restrict__ spec)
{
    const int lane = threadIdx.x & 63;
    const int wave = threadIdx.x >> 6;
    const int c16  = lane & 15;
    const int quad = lane >> 4;
    const int p    = blockIdx.x * 64 + wave * 16 + c16;   // sorted col
    const int ps   = p < NOUT ? p : NOUT - 1;             // clamp loads
    const int nc   = sorted_to_orig(ps);                  // orig W4/b4 row

    const float*  wp = W   + (size_t)nc * 4096 + quad * 8;
    const bf16_t* ap = Abf + (size_t)c16 * 4096 + quad * 8;

    f32x4 acc[4] = {};

    for (int s = 0; s < 128; ++s) {                // 128 k-steps of 32
        float4 w0 = *(const float4*)(wp);
        float4 w1 = *(const float4*)(wp + 4);
        wp += 32;
        bf16x8 bv;
        bv[0] = (bf16_t)w0.x; bv[1] = (bf16_t)w0.y;
        bv[2] = (bf16_t)w0.z; bv[3] = (bf16_t)w0.w;
        bv[4] = (bf16_t)w1.x; bv[5] = (bf16_t)w1.y;
        bv[6] = (bf16_t)w1.z; bv[7] = (bf16_t)w1.w;
#pragma unroll
        for (int mt = 0; mt < 4; ++mt) {
            bf16x8 av = *(const bf16x8*)(ap + (size_t)mt * 16 * 4096 + s * 32);
            acc[mt] = __builtin_amdgcn_mfma_f32_16x16x32_bf16(av, bv, acc[mt], 0, 0, 0);
        }
    }

    if (p < NOUT) {
        float bq = bias[nc];
#pragma unroll
        for (int mt = 0; mt < 4; ++mt)
#pragma unroll
            for (int r = 0; r < 4; ++r) {
                int m = mt * 16 + quad * 4 + r;
                spec[(size_t)m * NOUT + p] = acc[mt][r] + bq;
            }
    }
}

// ---------------- analytic sorted-grid ------------------------------------
// Sorted segments: (start, step, count, base)
//  (4700,.05,4601,0)(5630,.05,5001,4601)(6420,.05,7601,9602)(7500,.05,8401,17203)
//  (15050,.2,4001,25604)(15870,.2,2851,29605)(16475,.2,3126,32456)
// Grid value must be bit-exact vs host: f64 start + step*k, then f32 cast.
// __dadd_rn/__dmul_rn forbid FMA contraction (would change bits vs host).
__device__ __forceinline__ float grid_val(int p) {
    double s, st; int b;
    if (p < ROT) {
        st = 0.05;
        if      (p < 4601)  { s = 4700.0; b = 0; }
        else if (p < 9602)  { s = 5630.0; b = 4601; }
        else if (p < 17203) { s = 6420.0; b = 9602; }
        else                { s = 7500.0; b = 17203; }
    } else {
        st = 0.2;
        if      (p < 29605) { s = 15050.0; b = 25604; }
        else if (p < 32456) { s = 15870.0; b = 29605; }
        else                { s = 16475.0; b = 32456; }
    }
    return (float)__dadd_rn(s, __dmul_rn(st, (double)(p - b)));
}

// Exact searchsorted-left: first i with gs[i] >= x.
__device__ __forceinline__ int search_idx(float x) {
    if (!(x > 4700.0f)) return 0;
    double s = 4700.0, st = 0.05; int b = 0, n = 4601;
    if (x > 5630.0f)  { s = 5630.0;            b = 4601;  n = 5001; }
    if (x > 6420.0f)  { s = 6420.0;            b = 9602;  n = 7601; }
    if (x > 7500.0f)  { s = 7500.0;            b = 17203; n = 8401; }
    if (x > 15050.0f) { s = 15050.0; st = 0.2; b = 25604; n = 4001; }
    if (x > 15870.0f) { s = 15870.0;           b = 29605; n = 2851; }
    if (x > 16475.0f) { s = 16475.0;           b = 32456; n = 3126; }
    // past the last point of this segment -> first point of next segment
    float gl = (float)__dadd_rn(s, __dmul_rn(st, (double)(n - 1)));
    if (x > gl) return b + n;
    // candidate from continuous math, exact +-1 fixups vs f32 grid values
    double tt = ceil(((double)x - s) / st);
    int ti = (int)tt;
    ti = ti < 1 ? 1 : (ti > n - 1 ? n - 1 : ti);
#pragma unroll
    for (int r = 0; r < 2; ++r)
        if (ti >= 2 && (float)__dadd_rn(s, __dmul_rn(st, (double)(ti - 1))) >= x) --ti;
#pragma unroll
    for (int r = 0; r < 2; ++r)
        if (ti < n - 1 && (float)__dadd_rn(s, __dmul_rn(st, (double)ti)) < x) ++ti;
    return b + ti;
}

// ---------------- interpolation (spec in sorted layout) --------------------
__global__ __launch_bounds__(256) void interp_kernel(
    const float* __restrict__ spec, const float* __restrict__ obs,
    float* __restrict__ out)
{
    int idx = blockIdx.x * 256 + threadIdx.x;
    if (idx >= BATCH * NOBS) return;
    int m = idx >> 12;                 // NOBS = 4096
    float x = obs[idx];

    int i = search_idx(x);
    int j = i < 1 ? 1 : (i > NOUT - 1 ? NOUT - 1 : i);

    float x0 = grid_val(j - 1);
    float x1 = grid_val(j);
    const float* sp = spec + (size_t)m * NOUT;
    float y0 = sp[j - 1], y1 = sp[j];
    float t = (x - x0) / (x1 - x0);
    out[idx] = y0 + t * (y1 - y0);
}

// ---------------------------------------------------------------------------
extern "C" void kernel_launch(void* const* d_in, const int* in_sizes, int n_in,
                              void* d_out, int out_size, void* d_ws, size_t ws_size,
                              hipStream_t stream)
{
    const float* W0 = (const float*)d_in[0];
    const float* b0 = (const float*)d_in[1];
    const float* W1 = (const float*)d_in[2];
    const float* b1 = (const float*)d_in[3];
    const float* W2 = (const float*)d_in[4];
    const float* b2 = (const float*)d_in[5];
    const float* W3 = (const float*)d_in[6];
    const float* b3 = (const float*)d_in[7];
    const float* W4 = (const float*)d_in[8];
    const float* b4 = (const float*)d_in[9];
    const float* z  = (const float*)d_in[10];
    const float* obs  = (const float*)d_in[11];
    float* out = (float*)d_out;

    char* ws = (char*)d_ws;
    float*    pA   = (float*)(ws);                 // 4 MB  (L0: 512KB, L2: 4MB)
    float*    pB   = (float*)(ws + 4194304);       // 8 MB  (L1: 2MB,  L3: 8MB)
    float*    h1   = (float*)(ws + 12582912);      // 128 KB
    float*    h2   = (float*)(ws + 12713984);      // 256 KB
    float*    h3   = (float*)(ws + 12976128);      // 512 KB
    bf16_t*   h4b  = (bf16_t*)(ws + 13500416);     // 512 KB
    float*    spec = (float*)(ws + 14024704);      // 64*35582*4 = 9108992
    unsigned* sync = (unsigned*)(ws + 23133696);   // 8 B (counter, generation)

    init_sync<<<dim3(1), 1, 0, stream>>>(sync);

    fc_fused<<<dim3(256), 512, 0, stream>>>(
        z, W0, b0, W1, b1, W2, b2, W3, b3,
        pA, pB, h1, h2, h3, h4b, sync);

    // layer 4: bf16 MFMA, full K, bias fused, sorted-column stores
    layer4_kernel<<<dim3((NOUT + 63) / 64), 256, 0, stream>>>(h4b, W4, b4, spec);

    // interp: analytic searchsorted, no gs buffer
    interp_kernel<<<dim3((BATCH * NOBS + 255) / 256), 256, 0, stream>>>(spec, obs, out);
}

// Round 5
// 988.710 us; speedup vs baseline: 1.2374x; 1.2374x over previous
//
#include <hip/hip_runtime.h>

// ---------------------------------------------------------------------------
// SpectrumGenerator: 5-layer MLP (leaky_relu 0.2) + linear interp.
// dims: 128 -> 512 -> 1024 -> 2048 -> 4096 -> 35582 ; batch 64 ; 4096 obs pts
//
// R7 = R6 resubmit (R6 bench was an infra 'container failed twice' with no
// compile/test signal; R1 precedent: identical resubmit passed).
//
// R6 vs R2 skeleton (separate gemm + epi kernels; partials reduced once):
//  - fc_gemm: software-pipelined ping-pong LDS (prefetch next tile to regs
//    during compute; ONE syncthreads per k-iter). Was load->sync->compute.
//  - deeper split-K: L1/L2/L3 use S=16 (serial k-iters per block 15 -> 8,
//    L3 grid 512 -> 1024 blocks). Epi reads grow ~8 MB total (L2-resident).
//  - keep R4's verified analytic searchsorted interp + sorted-column layer4
//    (absmax identical to R2's; no gs buffer, no build_sorted kernel).
// Lessons kept: no epi-into-staging fusion (R4: +50us), no persistent
// cross-XCD barrier kernel (R5: +250us).
// ---------------------------------------------------------------------------

#define NOUT   35582
#define BATCH  64
#define NOBS   4096
#define ROT    25604   // count of low-wavelength block (sorted first)
#define HIOFF  9978    // orig offset of low-wavelength block

typedef __bf16 bf16_t;
typedef __attribute__((ext_vector_type(8))) __bf16 bf16x8;
typedef __attribute__((ext_vector_type(4))) __bf16 bf16x4;
typedef __attribute__((ext_vector_type(4))) float f32x4;

__device__ __forceinline__ int sorted_to_orig(int p) {
    return (p < ROT) ? (p + HIOFF) : (p - ROT);
}

// ---------------- fp32 FC partial GEMM: part[by] = A @ W^T (K-chunk) -------
// A: 64 x K, W: N x K (row-major). Block: 256 thr, 64x64 tile, BK = 32.
// gridDim.y k-chunks of KC; partial tile stored to part + by*64*N.
// Ping-pong LDS + register prefetch: one syncthreads per k-iteration.
__global__ __launch_bounds__(256) void fc_gemm(
    const float* __restrict__ A, const float* __restrict__ W,
    float* __restrict__ part, int K, int N, int KC)
{
    __shared__ float As[2][32][68];   // [buf][k][m]
    __shared__ float Bs[2][32][68];   // [buf][k][n]

    const int t  = threadIdx.x;
    const int n0 = blockIdx.x * 64;
    const int kbase = blockIdx.y * KC;
    const int tx = t & 15;
    const int ty = t >> 4;
    const int iters = KC >> 5;

    int mA[2], kA[2];
#pragma unroll
    for (int f = 0; f < 2; ++f) {
        int e = (t + 256 * f) * 4;
        mA[f] = e >> 5;            // row within 64-row tile
        kA[f] = e & 31;            // k within 32-wide slab (multiple of 4)
    }

    // prologue: tile 0 -> regs -> LDS[0]
    float4 ra[2], rb[2];
#pragma unroll
    for (int f = 0; f < 2; ++f) {
        ra[f] = *(const float4*)(A + (size_t)mA[f] * K + kbase + kA[f]);
        rb[f] = *(const float4*)(W + (size_t)(n0 + mA[f]) * K + kbase + kA[f]);
    }
#pragma unroll
    for (int f = 0; f < 2; ++f) {
        As[0][kA[f] + 0][mA[f]] = ra[f].x; As[0][kA[f] + 1][mA[f]] = ra[f].y;
        As[0][kA[f] + 2][mA[f]] = ra[f].z; As[0][kA[f] + 3][mA[f]] = ra[f].w;
        Bs[0][kA[f] + 0][mA[f]] = rb[f].x; Bs[0][kA[f] + 1][mA[f]] = rb[f].y;
        Bs[0][kA[f] + 2][mA[f]] = rb[f].z; Bs[0][kA[f] + 3][mA[f]] = rb[f].w;
    }
    __syncthreads();

    float acc[4][4] = {};
    int buf = 0;

    for (int it = 0; it < iters; ++it) {
        const bool more = (it + 1 < iters);
        if (more) {                 // prefetch next tile into regs (hides lat)
            int kn = kbase + (it + 1) * 32;
#pragma unroll
            for (int f = 0; f < 2; ++f) {
                ra[f] = *(const float4*)(A + (size_t)mA[f] * K + kn + kA[f]);
                rb[f] = *(const float4*)(W + (size_t)(n0 + mA[f]) * K + kn + kA[f]);
            }
        }
#pragma unroll
        for (int kk = 0; kk < 32; ++kk) {
            float4 av = *(const float4*)&As[buf][kk][ty * 4];
            float4 bv = *(const float4*)&Bs[buf][kk][tx * 4];
            float a[4] = {av.x, av.y, av.z, av.w};
            float b[4] = {bv.x, bv.y, bv.z, bv.w};
#pragma unroll
            for (int i = 0; i < 4; ++i)
#pragma unroll
                for (int j = 0; j < 4; ++j) acc[i][j] += a[i] * b[j];
        }
        if (more) {                 // write prefetched tile to other buffer
            int nb = buf ^ 1;
#pragma unroll
            for (int f = 0; f < 2; ++f) {
                As[nb][kA[f] + 0][mA[f]] = ra[f].x; As[nb][kA[f] + 1][mA[f]] = ra[f].y;
                As[nb][kA[f] + 2][mA[f]] = ra[f].z; As[nb][kA[f] + 3][mA[f]] = ra[f].w;
                Bs[nb][kA[f] + 0][mA[f]] = rb[f].x; Bs[nb][kA[f] + 1][mA[f]] = rb[f].y;
                Bs[nb][kA[f] + 2][mA[f]] = rb[f].z; Bs[nb][kA[f] + 3][mA[f]] = rb[f].w;
            }
            __syncthreads();
            buf = nb;
        }
    }

    float* p = part + (size_t)blockIdx.y * 64 * N;
#pragma unroll
    for (int i = 0; i < 4; ++i) {
        int m = ty * 4 + i;
#pragma unroll
        for (int j = 0; j < 4; ++j)
            p[(size_t)m * N + n0 + tx * 4 + j] = acc[i][j];
    }
}

// ---------------- FC epilogue: h = leaky(sum_s part[s] + b) ----------------
// one thread per 4 consecutive elements of the flattened 64xN output.
__global__ __launch_bounds__(256) void fc_epi(
    const float* __restrict__ part, const float* __restrict__ bias,
    float* __restrict__ out, bf16_t* __restrict__ out_bf, int N, int S)
{
    int idx = (blockIdx.x * 256 + threadIdx.x) * 4;   // flat elem index
    int n = idx & (N - 1);                            // N is a power of 2
    float4 v = make_float4(0.f, 0.f, 0.f, 0.f);
    for (int s = 0; s < S; ++s) {
        float4 p = *(const float4*)(part + (size_t)s * 64 * N + idx);
        v.x += p.x; v.y += p.y; v.z += p.z; v.w += p.w;
    }
    float4 b = *(const float4*)(bias + n);
    v.x += b.x; v.y += b.y; v.z += b.z; v.w += b.w;
    v.x = v.x > 0.f ? v.x : 0.2f * v.x;
    v.y = v.y > 0.f ? v.y : 0.2f * v.y;
    v.z = v.z > 0.f ? v.z : 0.2f * v.z;
    v.w = v.w > 0.f ? v.w : 0.2f * v.w;
    if (out) *(float4*)(out + idx) = v;
    if (out_bf) {
        bf16x4 o;
        o[0] = (bf16_t)v.x; o[1] = (bf16_t)v.y;
        o[2] = (bf16_t)v.z; o[3] = (bf16_t)v.w;
        *(bf16x4*)(out_bf + idx) = o;
    }
}

// ---------------- layer 4: spec_sorted = Abf(64x4096) @ W4^T + b4 ----------
// mfma_f32_16x16x32_bf16. Wave handles 16 consecutive SORTED cols p; the W4
// row is sorted_to_orig(p) (two contiguous runs -> streaming stays coalesced).
__global__ __launch_bounds__(256) void layer4_kernel(
    const bf16_t* __restrict__ Abf, const float* __restrict__ W,
    const float* __restrict__ bias, float* __restrict__ spec)
{
    const int lane = threadIdx.x & 63;
    const int wave = threadIdx.x >> 6;
    const int c16  = lane & 15;
    const int quad = lane >> 4;
    const int p    = blockIdx.x * 64 + wave * 16 + c16;   // sorted col
    const int ps   = p < NOUT ? p : NOUT - 1;             // clamp loads
    const int nc   = sorted_to_orig(ps);                  // orig W4/b4 row

    const float*  wp = W   + (size_t)nc * 4096 + quad * 8;
    const bf16_t* ap = Abf + (size_t)c16 * 4096 + quad * 8;

    f32x4 acc[4] = {};

    for (int s = 0; s < 128; ++s) {                // 128 k-steps of 32
        float4 w0 = *(const float4*)(wp);
        float4 w1 = *(const float4*)(wp + 4);
        wp += 32;
        bf16x8 bv;
        bv[0] = (bf16_t)w0.x; bv[1] = (bf16_t)w0.y;
        bv[2] = (bf16_t)w0.z; bv[3] = (bf16_t)w0.w;
        bv[4] = (bf16_t)w1.x; bv[5] = (bf16_t)w1.y;
        bv[6] = (bf16_t)w1.z; bv[7] = (bf16_t)w1.w;
#pragma unroll
        for (int mt = 0; mt < 4; ++mt) {
            bf16x8 av = *(const bf16x8*)(ap + (size_t)mt * 16 * 4096 + s * 32);
            acc[mt] = __builtin_amdgcn_mfma_f32_16x16x32_bf16(av, bv, acc[mt], 0, 0, 0);
        }
    }

    if (p < NOUT) {
        float bq = bias[nc];
#pragma unroll
        for (int mt = 0; mt < 4; ++mt)
#pragma unroll
            for (int r = 0; r < 4; ++r) {
                int m = mt * 16 + quad * 4 + r;
                spec[(size_t)m * NOUT + p] = acc[mt][r] + bq;
            }
    }
}

// ---------------- analytic sorted-grid ------------------------------------
// Sorted segments: (start, step, count, base)
//  (4700,.05,4601,0)(5630,.05,5001,4601)(6420,.05,7601,9602)(7500,.05,8401,17203)
//  (15050,.2,4001,25604)(15870,.2,2851,29605)(16475,.2,3126,32456)
// Grid value must be bit-exact vs host: f64 start + step*k, then f32 cast.
// __dadd_rn/__dmul_rn forbid FMA contraction (would change bits vs host).
__device__ __forceinline__ float grid_val(int p) {
    double s, st; int b;
    if (p < ROT) {
        st = 0.05;
        if      (p < 4601)  { s = 4700.0; b = 0; }
        else if (p < 9602)  { s = 5630.0; b = 4601; }
        else if (p < 17203) { s = 6420.0; b = 9602; }
        else                { s = 7500.0; b = 17203; }
    } else {
        st = 0.2;
        if      (p < 29605) { s = 15050.0; b = 25604; }
        else if (p < 32456) { s = 15870.0; b = 29605; }
        else                { s = 16475.0; b = 32456; }
    }
    return (float)__dadd_rn(s, __dmul_rn(st, (double)(p - b)));
}

// Exact searchsorted-left: first i with gs[i] >= x.
__device__ __forceinline__ int search_idx(float x) {
    if (!(x > 4700.0f)) return 0;
    double s = 4700.0, st = 0.05; int b = 0, n = 4601;
    if (x > 5630.0f)  { s = 5630.0;            b = 4601;  n = 5001; }
    if (x > 6420.0f)  { s = 6420.0;            b = 9602;  n = 7601; }
    if (x > 7500.0f)  { s = 7500.0;            b = 17203; n = 8401; }
    if (x > 15050.0f) { s = 15050.0; st = 0.2; b = 25604; n = 4001; }
    if (x > 15870.0f) { s = 15870.0;           b = 29605; n = 2851; }
    if (x > 16475.0f) { s = 16475.0;           b = 32456; n = 3126; }
    // past the last point of this segment -> first point of next segment
    float gl = (float)__dadd_rn(s, __dmul_rn(st, (double)(n - 1)));
    if (x > gl) return b + n;
    // candidate from continuous math, exact +-1 fixups vs f32 grid values
    double tt = ceil(((double)x - s) / st);
    int ti = (int)tt;
    ti = ti < 1 ? 1 : (ti > n - 1 ? n - 1 : ti);
#pragma unroll
    for (int r = 0; r < 2; ++r)
        if (ti >= 2 && (float)__dadd_rn(s, __dmul_rn(st, (double)(ti - 1))) >= x) --ti;
#pragma unroll
    for (int r = 0; r < 2; ++r)
        if (ti < n - 1 && (float)__dadd_rn(s, __dmul_rn(st, (double)ti)) < x) ++ti;
    return b + ti;
}

// ---------------- interpolation (spec in sorted layout) --------------------
__global__ __launch_bounds__(256) void interp_kernel(
    const float* __restrict__ spec, const float* __restrict__ obs,
    float* __restrict__ out)
{
    int idx = blockIdx.x * 256 + threadIdx.x;
    if (idx >= BATCH * NOBS) return;
    int m = idx >> 12;                 // NOBS = 4096
    float x = obs[idx];

    int i = search_idx(x);
    int j = i < 1 ? 1 : (i > NOUT - 1 ? NOUT - 1 : i);

    float x0 = grid_val(j - 1);
    float x1 = grid_val(j);
    const float* sp = spec + (size_t)m * NOUT;
    float y0 = sp[j - 1], y1 = sp[j];
    float t = (x - x0) / (x1 - x0);
    out[idx] = y0 + t * (y1 - y0);
}

// ---------------------------------------------------------------------------
extern "C" void kernel_launch(void* const* d_in, const int* in_sizes, int n_in,
                              void* d_out, int out_size, void* d_ws, size_t ws_size,
                              hipStream_t stream)
{
    const float* W0 = (const float*)d_in[0];
    const float* b0 = (const float*)d_in[1];
    const float* W1 = (const float*)d_in[2];
    const float* b1 = (const float*)d_in[3];
    const float* W2 = (const float*)d_in[4];
    const float* b2 = (const float*)d_in[5];
    const float* W3 = (const float*)d_in[6];
    const float* b3 = (const float*)d_in[7];
    const float* W4 = (const float*)d_in[8];
    const float* b4 = (const float*)d_in[9];
    const float* z  = (const float*)d_in[10];
    const float* obs  = (const float*)d_in[11];
    float* out = (float*)d_out;

    char* ws = (char*)d_ws;
    float*  pA   = (float*)(ws);                 // max 16*64*2048*4 = 8 MB
    float*  pB   = (float*)(ws + 8388608);       // max 16*64*4096*4 = 16 MB
    float*  h1   = (float*)(ws + 25165824);      // 128 KB
    float*  h2   = (float*)(ws + 25296896);      // 256 KB
    float*  h3   = (float*)(ws + 25559040);      // 512 KB
    bf16_t* h4b  = (bf16_t*)(ws + 26083328);     // 512 KB
    float*  spec = (float*)(ws + 26607616);      // 64*35582*4 = 9108992

    // L0: K=128,  N=512,  S=4,  KC=32  -> grid 8x4,   1 k-iter/block
    fc_gemm<<<dim3(8, 4),   256, 0, stream>>>(z,  W0, pA, 128,  512,  32);
    fc_epi <<<dim3(32),  256, 0, stream>>>(pA, b0, h1, nullptr, 512, 4);
    // L1: K=512,  N=1024, S=16, KC=32  -> grid 16x16, 1 k-iter/block
    fc_gemm<<<dim3(16, 16), 256, 0, stream>>>(h1, W1, pB, 512,  1024, 32);
    fc_epi <<<dim3(64),  256, 0, stream>>>(pB, b1, h2, nullptr, 1024, 16);
    // L2: K=1024, N=2048, S=16, KC=64  -> grid 32x16, 2 k-iters/block
    fc_gemm<<<dim3(32, 16), 256, 0, stream>>>(h2, W2, pA, 1024, 2048, 64);
    fc_epi <<<dim3(128), 256, 0, stream>>>(pA, b2, h3, nullptr, 2048, 16);
    // L3: K=2048, N=4096, S=16, KC=128 -> grid 64x16, 4 k-iters/block
    fc_gemm<<<dim3(64, 16), 256, 0, stream>>>(h3, W3, pB, 2048, 4096, 128);
    fc_epi <<<dim3(256), 256, 0, stream>>>(pB, b3, nullptr, h4b, 4096, 16);

    // layer 4: bf16 MFMA, full K, bias fused, sorted-column stores
    layer4_kernel<<<dim3((NOUT + 63) / 64), 256, 0, stream>>>(h4b, W4, b4, spec);

    // interp: analytic searchsorted, no gs buffer
    interp_kernel<<<dim3((BATCH * NOBS + 255) / 256), 256, 0, stream>>>(spec, obs, out);
}